// Round 1
// baseline (7298.171 us; speedup 1.0000x reference)
//
#include <hip/hip_runtime.h>
#include <hip/hip_bf16.h>

#define NN 49152
#define GG 1024
#define EE 65536
#define ETOT 196608
#define FF 384
#define NEG_SLOPE 0.2f

__device__ __forceinline__ float wave_sum(float v) {
#pragma unroll
    for (int m = 32; m; m >>= 1) v += __shfl_xor(v, m);
    return v;
}

// ---------------- GEMM: C[m,j] = act(sum_k A[m,k]*W[k,j] + bias[j]) ----------------
// M fixed = NN (all GEMMs have M = 49152, divisible by 64).
// blockIdx.z batches over relations via wzs/czs strides.
template <int ACT>
__global__ __launch_bounds__(256) void gemm_k(
    const float* __restrict__ A, int K,
    const float* __restrict__ Wg, int Jw,
    const float* __restrict__ bias,
    float* __restrict__ Cg, int ldc, int jmax,
    size_t wzs, size_t czs)
{
    __shared__ float As[16][64];
    __shared__ float Bs[16][68];
    const float* W = Wg + (size_t)blockIdx.z * wzs;
    float* C = Cg + (size_t)blockIdx.z * czs;
    int tid = threadIdx.x;
    int bj = blockIdx.x << 6;
    int bm = blockIdx.y << 6;
    int tx = tid & 15, ty = tid >> 4;
    float acc[4][4] = {};
    int ktn = (K + 15) >> 4;
    int ar = tid >> 2;          // 0..63 : A row within tile
    int aks = (tid & 3) << 2;   // 0,4,8,12 : k chunk
    int wk = tid >> 4;          // 0..15 : W k row
    int wjs = (tid & 15) << 2;  // 0..60 : j chunk
    for (int kt = 0; kt < ktn; ++kt) {
        int k0 = kt << 4;
        const float* Ap = A + (size_t)(bm + ar) * K + k0 + aks;
#pragma unroll
        for (int i = 0; i < 4; ++i) {
            int k = k0 + aks + i;
            As[aks + i][ar] = (k < K) ? Ap[i] : 0.f;
        }
        const float* Wp = W + (size_t)(k0 + wk) * Jw + bj + wjs;
        bool kok = (k0 + wk) < K;
#pragma unroll
        for (int i = 0; i < 4; ++i) {
            int j = bj + wjs + i;
            Bs[wk][wjs + i] = (kok && j < jmax) ? Wp[i] : 0.f;
        }
        __syncthreads();
#pragma unroll
        for (int kk = 0; kk < 16; ++kk) {
            const float4 av = *reinterpret_cast<const float4*>(&As[kk][ty << 2]);
            const float4 bv = *reinterpret_cast<const float4*>(&Bs[kk][tx << 2]);
            float aa[4] = {av.x, av.y, av.z, av.w};
            float bb[4] = {bv.x, bv.y, bv.z, bv.w};
#pragma unroll
            for (int i = 0; i < 4; ++i)
#pragma unroll
                for (int j = 0; j < 4; ++j)
                    acc[i][j] = fmaf(aa[i], bb[j], acc[i][j]);
        }
        __syncthreads();
    }
#pragma unroll
    for (int i = 0; i < 4; ++i) {
        int row = bm + (ty << 2) + i;
#pragma unroll
        for (int j = 0; j < 4; ++j) {
            int col = bj + (tx << 2) + j;
            if (col < jmax) {
                float v = acc[i][j];
                if (bias) v += bias[col];
                if (ACT == 1) v = fmaxf(v, 0.f);
                C[(size_t)row * ldc + col] = v;
            }
        }
    }
}

// ---------------- node counting per graph ----------------
__global__ void count_nodes(const int* __restrict__ batch, float* __restrict__ gcnt) {
    int n = blockIdx.x * 256 + threadIdx.x;
    if (n < NN) atomicAdd(&gcnt[batch[n]], 1.f);
}

// ---------------- encoder global-LN stats ----------------
__global__ __launch_bounds__(256) void enc_reduce(const float* __restrict__ h0, int c0, float* __restrict__ est) {
    float s1 = 0.f, s2 = 0.f;
    for (long i = blockIdx.x * 256 + threadIdx.x; i < (long)NN * 128; i += (long)gridDim.x * 256) {
        int n = (int)(i >> 7), j = (int)(i & 127);
        float v = h0[(size_t)n * FF + c0 + j];
        s1 += v; s2 += v * v;
    }
    s1 = wave_sum(s1);
    s2 = wave_sum(s2);
    if ((threadIdx.x & 63) == 0) { atomicAdd(&est[0], s1); atomicAdd(&est[1], s2); }
}

__global__ void enc_finalize(float* est) {
    int i = threadIdx.x;
    if (i < 3) {
        float cnt = (float)NN * 128.f;
        float mean = est[2 * i] / cnt;
        float var = est[2 * i + 1] / cnt - mean * mean;
        var = fmaxf(var, 0.f);
        est[6 + 2 * i] = mean;
        est[7 + 2 * i] = 1.f / (sqrtf(var) + 1e-5f);  // jnp.std + EPS
    }
}

__global__ __launch_bounds__(256) void enc_apply(
    float* __restrict__ h0, const float* __restrict__ est,
    const float* __restrict__ lw0, const float* __restrict__ lb0,
    const float* __restrict__ lw1, const float* __restrict__ lb1,
    const float* __restrict__ lw2, const float* __restrict__ lb2)
{
    long gt = (long)blockIdx.x * 256 + threadIdx.x;
    if (gt >= (long)NN * FF) return;
    int f = (int)(gt % FF);
    int enc = f >> 7, j = f & 127;
    const float* lw = enc == 0 ? lw0 : (enc == 1 ? lw1 : lw2);
    const float* lb = enc == 0 ? lb0 : (enc == 1 ? lb1 : lb2);
    float mean = est[6 + 2 * enc], sc = est[7 + 2 * enc];
    h0[gt] = (h0[gt] - mean) * sc * lw[j] + lb[j];
}

// ---------------- qi/kj: per-(relation,node) attention dots ----------------
__global__ __launch_bounds__(128) void qk_kernel(
    const float* __restrict__ xt, const float* __restrict__ q, const float* __restrict__ k,
    float* __restrict__ qi, float* __restrict__ kj)
{
    __shared__ float qsT[8 * FF];
    __shared__ float ksT[8 * FF];
    for (int i = threadIdx.x; i < 8 * FF; i += 128) {
        int h = i & 7, f = i >> 3;
        qsT[h * FF + f] = q[i];
        ksT[h * FF + f] = k[i];
    }
    __syncthreads();
    int wid = (blockIdx.x * 128 + threadIdx.x) >> 6;  // (r*NN + n)
    int lane = threadIdx.x & 63;
    const float* row = xt + (size_t)wid * FF;
    float aq[8] = {}, ak[8] = {};
#pragma unroll
    for (int i = 0; i < 6; ++i) {
        int f = lane + (i << 6);
        float v = row[f];
#pragma unroll
        for (int h = 0; h < 8; ++h) {
            aq[h] = fmaf(v, qsT[h * FF + f], aq[h]);
            ak[h] = fmaf(v, ksT[h * FF + f], ak[h]);
        }
    }
#pragma unroll
    for (int h = 0; h < 8; ++h) {
        float sq = wave_sum(aq[h]);
        float sk = wave_sum(ak[h]);
        if (lane == 0) {
            qi[(size_t)wid * 8 + h] = sq;
            kj[(size_t)wid * 8 + h] = sk;
        }
    }
}

// ---------------- edge phase ----------------
__device__ __forceinline__ unsigned f2ord(float f) {
    unsigned u = __float_as_uint(f);
    return (u & 0x80000000u) ? ~u : (u | 0x80000000u);
}
__device__ __forceinline__ float ord2f(unsigned u) {
    return __uint_as_float((u & 0x80000000u) ? (u ^ 0x80000000u) : ~u);
}

__global__ __launch_bounds__(256) void edge_alpha_max(
    const int* __restrict__ eo, const int* __restrict__ ea, const int* __restrict__ es,
    const float* __restrict__ qi, const float* __restrict__ kj,
    float* __restrict__ alpha, unsigned* __restrict__ mu)
{
    int e = blockIdx.x * 256 + threadIdx.x;
    if (e >= ETOT) return;
    int et = e >> 16, le = e & 65535;
    const int* ei = et == 0 ? eo : (et == 1 ? ea : es);
    int src = ei[le], dst = ei[EE + le];
    const float* qrow = qi + ((size_t)et * NN + dst) * 8;
    const float* krow = kj + ((size_t)et * NN + src) * 8;
#pragma unroll
    for (int h = 0; h < 8; ++h) {
        float a = qrow[h] + krow[h];
        a = a >= 0.f ? a : NEG_SLOPE * a;
        alpha[(size_t)e * 8 + h] = a;
        atomicMax(&mu[dst * 8 + h], f2ord(a));
    }
}

__global__ __launch_bounds__(256) void edge_exp_sum(
    const int* __restrict__ eo, const int* __restrict__ ea, const int* __restrict__ es,
    const unsigned* __restrict__ mu, float* __restrict__ alpha, float* __restrict__ s)
{
    int e = blockIdx.x * 256 + threadIdx.x;
    if (e >= ETOT) return;
    int et = e >> 16, le = e & 65535;
    const int* ei = et == 0 ? eo : (et == 1 ? ea : es);
    int dst = ei[EE + le];
#pragma unroll
    for (int h = 0; h < 8; ++h) {
        float m = ord2f(mu[dst * 8 + h]);
        float av = __expf(alpha[(size_t)e * 8 + h] - m);
        alpha[(size_t)e * 8 + h] = av;
        atomicAdd(&s[dst * 8 + h], av);
    }
}

// one wave per edge; lane l handles features [6l, 6l+6), all in head l>>3
__global__ __launch_bounds__(256) void scatter_msg(
    const int* __restrict__ eo, const int* __restrict__ ea, const int* __restrict__ es,
    const float* __restrict__ alpha, const float* __restrict__ s,
    const float* __restrict__ xt, float* __restrict__ msg)
{
    long gt = (long)blockIdx.x * 256 + threadIdx.x;
    int e = (int)(gt >> 6);
    if (e >= ETOT) return;
    int lane = (int)(gt & 63);
    int et = e >> 16, le = e & 65535;
    const int* ei = et == 0 ? eo : (et == 1 ? ea : es);
    int src = ei[le], dst = ei[EE + le];
    int head = lane >> 3;
    float w = alpha[(size_t)e * 8 + head] / (s[dst * 8 + head] + 1e-16f);
    const float* xr = xt + ((size_t)et * NN + src) * FF + lane * 6;
    float* mr = msg + (size_t)dst * FF + lane * 6;
#pragma unroll
    for (int i = 0; i < 6; ++i) atomicAdd(&mr[i], w * xr[i]);
}

// ---------------- y = hin + elu(msg + rb); per-graph stats ----------------
__global__ __launch_bounds__(256) void post_kernel(
    const float* __restrict__ hin, float* __restrict__ ybuf, const float* __restrict__ rb,
    const int* __restrict__ batch, float* __restrict__ gs1, float* __restrict__ gs2)
{
    long gt = (long)blockIdx.x * 256 + threadIdx.x;
    int n = (int)(gt >> 6);
    if (n >= NN) return;
    int lane = (int)(gt & 63);
    int f0 = lane * 6;
    float s1 = 0.f, s2 = 0.f;
#pragma unroll
    for (int i = 0; i < 6; ++i) {
        int f = f0 + i;
        float mv = ybuf[(size_t)n * FF + f] + rb[f];
        float e = mv > 0.f ? mv : (__expf(mv) - 1.f);
        float y = hin[(size_t)n * FF + f] + e;
        ybuf[(size_t)n * FF + f] = y;
        s1 += y; s2 += y * y;
    }
    s1 = wave_sum(s1);
    s2 = wave_sum(s2);
    if (lane == 0) {
        int g = batch[n];
        atomicAdd(&gs1[g], s1);
        atomicAdd(&gs2[g], s2);
    }
}

__global__ void graph_finalize(
    const float* __restrict__ gcnt, const float* __restrict__ gs1, const float* __restrict__ gs2,
    float* __restrict__ gmean, float* __restrict__ grstd)
{
    int g = blockIdx.x * 64 + threadIdx.x;
    if (g >= GG) return;
    float cnt = fmaxf(gcnt[g], 1.f) * (float)FF;
    float mean = gs1[g] / cnt;
    float var = gs2[g] / cnt - mean * mean;
    var = fmaxf(var, 0.f);
    gmean[g] = mean;
    grstd[g] = 1.f / sqrtf(var + 1e-5f);  // sqrt(var + EPS)
}

__global__ __launch_bounds__(256) void ln_apply(
    const float* __restrict__ y, const int* __restrict__ batch,
    const float* __restrict__ gmean, const float* __restrict__ grstd,
    const float* __restrict__ w, const float* __restrict__ b, float* __restrict__ out)
{
    long gt = (long)blockIdx.x * 256 + threadIdx.x;
    int n = (int)(gt >> 6);
    if (n >= NN) return;
    int lane = (int)(gt & 63);
    int f0 = lane * 6;
    int g = batch[n];
    float mean = gmean[g], rs = grstd[g];
#pragma unroll
    for (int i = 0; i < 6; ++i) {
        int f = f0 + i;
        out[(size_t)n * FF + f] = (y[(size_t)n * FF + f] - mean) * rs * w[f] + b[f];
    }
}

// ---------------- host-side layer driver ----------------
static void rgat_layer(hipStream_t stream,
    const float* hin, const float* rw, const float* rq, const float* rk, const float* rb,
    const float* lnw, const float* lnb,
    const int* ei_o, const int* ei_a, const int* ei_s, const int* batch,
    float* xt, float* qi, float* kj, float* alpha, unsigned* mu, float* sden,
    float* msg, float* gs1, float* gs2, const float* gcnt, float* gmean, float* grstd,
    float* hout)
{
    hipMemsetAsync(msg, 0, (size_t)NN * FF * 4, stream);
    hipMemsetAsync(mu, 0, (size_t)NN * 8 * 4, stream);
    hipMemsetAsync(sden, 0, (size_t)NN * 8 * 4, stream);
    hipMemsetAsync(gs1, 0, GG * 4, stream);
    hipMemsetAsync(gs2, 0, GG * 4, stream);
    // xt[r] = hin @ rw[r]
    gemm_k<0><<<dim3(6, 768, 3), 256, 0, stream>>>(hin, FF, rw, FF, nullptr, xt, FF, FF,
                                                   (size_t)FF * FF, (size_t)NN * FF);
    qk_kernel<<<3 * NN / 2, 128, 0, stream>>>(xt, rq, rk, qi, kj);
    edge_alpha_max<<<ETOT / 256, 256, 0, stream>>>(ei_o, ei_a, ei_s, qi, kj, alpha, mu);
    edge_exp_sum<<<ETOT / 256, 256, 0, stream>>>(ei_o, ei_a, ei_s, mu, alpha, sden);
    scatter_msg<<<ETOT / 4, 256, 0, stream>>>(ei_o, ei_a, ei_s, alpha, sden, xt, msg);
    post_kernel<<<NN / 4, 256, 0, stream>>>(hin, msg, rb, batch, gs1, gs2);
    graph_finalize<<<GG / 64, 64, 0, stream>>>(gcnt, gs1, gs2, gmean, grstd);
    ln_apply<<<NN / 4, 256, 0, stream>>>(msg, batch, gmean, grstd, lnw, lnb, hout);
}

extern "C" void kernel_launch(void* const* d_in, const int* in_sizes, int n_in,
                              void* d_out, int out_size, void* d_ws, size_t ws_size,
                              hipStream_t stream)
{
    const float* x_visual = (const float*)d_in[0];
    const float* x_geom   = (const float*)d_in[1];
    const float* x_prior  = (const float*)d_in[2];
    const float* vis_w  = (const float*)d_in[3];
    const float* vis_b  = (const float*)d_in[4];
    const float* vis_lw = (const float*)d_in[5];
    const float* vis_lb = (const float*)d_in[6];
    const float* geom_w  = (const float*)d_in[7];
    const float* geom_b  = (const float*)d_in[8];
    const float* geom_lw = (const float*)d_in[9];
    const float* geom_lb = (const float*)d_in[10];
    const float* prior_w  = (const float*)d_in[11];
    const float* prior_b  = (const float*)d_in[12];
    const float* prior_lw = (const float*)d_in[13];
    const float* prior_lb = (const float*)d_in[14];
    const float* r1_w = (const float*)d_in[15];
    const float* r1_q = (const float*)d_in[16];
    const float* r1_k = (const float*)d_in[17];
    const float* r1_b = (const float*)d_in[18];
    const float* n1_w = (const float*)d_in[19];
    const float* n1_b = (const float*)d_in[20];
    const float* r2_w = (const float*)d_in[21];
    const float* r2_q = (const float*)d_in[22];
    const float* r2_k = (const float*)d_in[23];
    const float* r2_b = (const float*)d_in[24];
    const float* n2_w = (const float*)d_in[25];
    const float* n2_b = (const float*)d_in[26];
    const float* c_w1 = (const float*)d_in[27];
    const float* c_b1 = (const float*)d_in[28];
    const float* c_w2 = (const float*)d_in[29];
    const float* c_b2 = (const float*)d_in[30];
    const int* ei_o  = (const int*)d_in[31];
    const int* ei_a  = (const int*)d_in[32];
    const int* ei_s  = (const int*)d_in[33];
    const int* batch = (const int*)d_in[34];
    float* out = (float*)d_out;

    float* p = (float*)d_ws;
    float* h0 = p;    p += (size_t)NN * FF;
    float* xt = p;    p += (size_t)3 * NN * FF;
    float* h1 = p;    p += (size_t)NN * FF;
    float* msg = p;   p += (size_t)NN * FF;
    float* qi = p;    p += (size_t)3 * NN * 8;
    float* kj = p;    p += (size_t)3 * NN * 8;
    float* alpha = p; p += (size_t)ETOT * 8;
    unsigned* mu = (unsigned*)p; p += (size_t)NN * 8;
    float* sden = p;  p += (size_t)NN * 8;
    float* gs1 = p;   p += GG;
    float* gs2 = p;   p += GG;
    float* gcnt = p;  p += GG;
    float* gmean = p; p += GG;
    float* grstd = p; p += GG;
    float* est = p;   p += 16;
    float* t128 = xt;  // reuse (free during classifier)
    float* h2 = h0;    // reuse (h0 dead after layer-1 post)

    // per-graph node counts (shared by both layers)
    hipMemsetAsync(gcnt, 0, GG * 4, stream);
    count_nodes<<<NN / 256, 256, 0, stream>>>(batch, gcnt);

    // ---- encoders: h0 = concat(enc_vis, enc_geom, enc_prior) ----
    hipMemsetAsync(est, 0, 16 * 4, stream);
    gemm_k<1><<<dim3(2, 768, 1), 256, 0, stream>>>(x_visual, 1024, vis_w, 128, vis_b, h0 + 0, FF, 128, 0, 0);
    gemm_k<1><<<dim3(2, 768, 1), 256, 0, stream>>>(x_geom, 6, geom_w, 128, geom_b, h0 + 128, FF, 128, 0, 0);
    gemm_k<1><<<dim3(2, 768, 1), 256, 0, stream>>>(x_prior, 50, prior_w, 128, prior_b, h0 + 256, FF, 128, 0, 0);
    enc_reduce<<<512, 256, 0, stream>>>(h0, 0, est + 0);
    enc_reduce<<<512, 256, 0, stream>>>(h0, 128, est + 2);
    enc_reduce<<<512, 256, 0, stream>>>(h0, 256, est + 4);
    enc_finalize<<<1, 64, 0, stream>>>(est);
    enc_apply<<<(int)((size_t)NN * FF / 256), 256, 0, stream>>>(h0, est, vis_lw, vis_lb, geom_lw, geom_lb, prior_lw, prior_lb);

    // ---- RGAT layer 1 ----
    rgat_layer(stream, h0, r1_w, r1_q, r1_k, r1_b, n1_w, n1_b,
               ei_o, ei_a, ei_s, batch,
               xt, qi, kj, alpha, mu, sden, msg, gs1, gs2, gcnt, gmean, grstd, h1);
    // ---- RGAT layer 2 ----
    rgat_layer(stream, h1, r2_w, r2_q, r2_k, r2_b, n2_w, n2_b,
               ei_o, ei_a, ei_s, batch,
               xt, qi, kj, alpha, mu, sden, msg, gs1, gs2, gcnt, gmean, grstd, h2);

    // ---- classifier ----
    gemm_k<1><<<dim3(2, 768, 1), 256, 0, stream>>>(h2, FF, c_w1, 128, c_b1, t128, 128, 128, 0, 0);
    gemm_k<0><<<dim3(1, 768, 1), 256, 0, stream>>>(t128, 128, c_w2, 49, c_b2, out, 49, 49, 0, 0);
}

// Round 2
// 1808.150 us; speedup vs baseline: 4.0363x; 4.0363x over previous
//
#include <hip/hip_runtime.h>
#include <hip/hip_bf16.h>

#define NN 49152
#define GG 1024
#define EE 65536
#define ETOT 196608
#define FF 384
#define NEG_SLOPE 0.2f

typedef __attribute__((ext_vector_type(8))) short bf16x8;
typedef __attribute__((ext_vector_type(4))) float f32x4;

__device__ __forceinline__ float wave_sum(float v) {
#pragma unroll
    for (int m = 32; m; m >>= 1) v += __shfl_xor(v, m);
    return v;
}
__device__ __forceinline__ float wave_max(float v) {
#pragma unroll
    for (int m = 32; m; m >>= 1) v = fmaxf(v, __shfl_xor(v, m));
    return v;
}
__device__ __forceinline__ unsigned short f2bf(float f) {
    __hip_bfloat16 b = __float2bfloat16(f);
    return *reinterpret_cast<unsigned short*>(&b);
}
__device__ __forceinline__ float bflo(unsigned u) { return __uint_as_float(u << 16); }
__device__ __forceinline__ float bfhi(unsigned u) { return __uint_as_float(u & 0xffff0000u); }

// ================= MFMA bf16 GEMM: C = act(A @ Bt^T + bias) =================
// M = NN (multiple of 128). N = gridDim.x*128. Bt is [N][K] bf16 (k contiguous).
// LDS XOR swizzle: byte = row*64 + ((c16 ^ ((row>>1)&3))<<4)  [2-way, free]
__device__ __forceinline__ int swz(int row, int c16) {
    return row * 64 + ((c16 ^ ((row >> 1) & 3)) << 4);
}

template <int ACT, bool ABF, bool OBF>
__global__ __launch_bounds__(256) void gemm_mfma(
    const void* __restrict__ Ag, int K,
    const unsigned short* __restrict__ Btg,
    const float* __restrict__ bias,
    void* __restrict__ Cg, int ldc,
    size_t bzs, size_t czs)
{
    __shared__ __align__(16) char As[8192];
    __shared__ __align__(16) char Bs[8192];
    const unsigned short* Bt = Btg + (size_t)blockIdx.z * bzs;
    int t = threadIdx.x;
    int bm = blockIdx.y << 7, bn = blockIdx.x << 7;
    int lane = t & 63, wid = t >> 6, wr = wid >> 1, wc = wid & 1;
    f32x4 acc[4][4] = {};
    int ktn = K >> 5;
    for (int kt = 0; kt < ktn; ++kt) {
        int k0 = kt << 5;
#pragma unroll
        for (int ii = 0; ii < 2; ++ii) {
            int id = t + (ii << 8);
            int row = id >> 2, c16 = id & 3;
            char* dstA = As + swz(row, c16);
            if (ABF) {
                const unsigned short* srcA = (const unsigned short*)Ag + (size_t)(bm + row) * K + k0 + c16 * 8;
                *(int4*)dstA = *(const int4*)srcA;
            } else {
                const float* srcA = (const float*)Ag + (size_t)(bm + row) * K + k0 + c16 * 8;
                float4 a0 = *(const float4*)srcA;
                float4 a1 = *(const float4*)(srcA + 4);
                union { unsigned short u[8]; int4 v; } P;
                P.u[0] = f2bf(a0.x); P.u[1] = f2bf(a0.y); P.u[2] = f2bf(a0.z); P.u[3] = f2bf(a0.w);
                P.u[4] = f2bf(a1.x); P.u[5] = f2bf(a1.y); P.u[6] = f2bf(a1.z); P.u[7] = f2bf(a1.w);
                *(int4*)dstA = P.v;
            }
            const unsigned short* srcB = Bt + (size_t)(bn + row) * K + k0 + c16 * 8;
            *(int4*)(Bs + swz(row, c16)) = *(const int4*)srcB;
        }
        __syncthreads();
        int c16 = lane >> 4;
        bf16x8 af[4], bfr[4];
#pragma unroll
        for (int m = 0; m < 4; ++m)
            af[m] = *(const bf16x8*)(As + swz((wr << 6) + (m << 4) + (lane & 15), c16));
#pragma unroll
        for (int n = 0; n < 4; ++n)
            bfr[n] = *(const bf16x8*)(Bs + swz((wc << 6) + (n << 4) + (lane & 15), c16));
#pragma unroll
        for (int m = 0; m < 4; ++m)
#pragma unroll
            for (int n = 0; n < 4; ++n)
                acc[m][n] = __builtin_amdgcn_mfma_f32_16x16x32_bf16(af[m], bfr[n], acc[m][n], 0, 0, 0);
        __syncthreads();
    }
    // epilogue: D lane map (m89): col = lane&15, row = (lane>>4)*4 + reg
#pragma unroll
    for (int m = 0; m < 4; ++m) {
#pragma unroll
        for (int n = 0; n < 4; ++n) {
            int row0 = bm + (wr << 6) + (m << 4) + ((lane >> 4) << 2);
            int col = bn + (wc << 6) + (n << 4) + (lane & 15);
            float bv = bias ? bias[col] : 0.f;
#pragma unroll
            for (int j = 0; j < 4; ++j) {
                float v = acc[m][n][j] + bv;
                if (ACT == 1) v = fmaxf(v, 0.f);
                if (OBF) {
                    unsigned short* C = (unsigned short*)Cg + (size_t)blockIdx.z * czs;
                    C[(size_t)(row0 + j) * ldc + col] = f2bf(v);
                } else {
                    float* C = (float*)Cg + (size_t)blockIdx.z * czs;
                    C[(size_t)(row0 + j) * ldc + col] = v;
                }
            }
        }
    }
}

// ================= f32 fallback GEMM (small K / small N) =================
template <int ACT>
__global__ __launch_bounds__(256) void gemm_k(
    const float* __restrict__ A, int K,
    const float* __restrict__ Wg, int Jw,
    const float* __restrict__ bias,
    float* __restrict__ Cg, int ldc, int jmax,
    size_t wzs, size_t czs)
{
    __shared__ float Ash[16][64];
    __shared__ float Bsh[16][68];
    const float* W = Wg + (size_t)blockIdx.z * wzs;
    float* C = Cg + (size_t)blockIdx.z * czs;
    int tid = threadIdx.x;
    int bj = blockIdx.x << 6;
    int bm = blockIdx.y << 6;
    int tx = tid & 15, ty = tid >> 4;
    float acc[4][4] = {};
    int ktn = (K + 15) >> 4;
    int ar = tid >> 2;
    int aks = (tid & 3) << 2;
    int wk = tid >> 4;
    int wjs = (tid & 15) << 2;
    for (int kt = 0; kt < ktn; ++kt) {
        int k0 = kt << 4;
        const float* Ap = A + (size_t)(bm + ar) * K + k0 + aks;
#pragma unroll
        for (int i = 0; i < 4; ++i) {
            int k = k0 + aks + i;
            Ash[aks + i][ar] = (k < K) ? Ap[i] : 0.f;
        }
        const float* Wp = W + (size_t)(k0 + wk) * Jw + bj + wjs;
        bool kok = (k0 + wk) < K;
#pragma unroll
        for (int i = 0; i < 4; ++i) {
            int j = bj + wjs + i;
            Bsh[wk][wjs + i] = (kok && j < jmax) ? Wp[i] : 0.f;
        }
        __syncthreads();
#pragma unroll
        for (int kk = 0; kk < 16; ++kk) {
            const float4 av = *reinterpret_cast<const float4*>(&Ash[kk][ty << 2]);
            const float4 bv = *reinterpret_cast<const float4*>(&Bsh[kk][tx << 2]);
            float aa[4] = {av.x, av.y, av.z, av.w};
            float bb[4] = {bv.x, bv.y, bv.z, bv.w};
#pragma unroll
            for (int i = 0; i < 4; ++i)
#pragma unroll
                for (int j = 0; j < 4; ++j)
                    acc[i][j] = fmaf(aa[i], bb[j], acc[i][j]);
        }
        __syncthreads();
    }
#pragma unroll
    for (int i = 0; i < 4; ++i) {
        int row = bm + (ty << 2) + i;
#pragma unroll
        for (int j = 0; j < 4; ++j) {
            int col = bj + (tx << 2) + j;
            if (col < jmax) {
                float v = acc[i][j];
                if (bias) v += bias[col];
                if (ACT == 1) v = fmaxf(v, 0.f);
                C[(size_t)row * ldc + col] = v;
            }
        }
    }
}

// ================= weight transpose + bf16 convert: Wt[z][n][k] = W[z][k][n] =================
__global__ void transpose_bf(const float* __restrict__ W, unsigned short* __restrict__ Wt,
                             int K, int N, int total) {
    int i = blockIdx.x * 256 + threadIdx.x;
    if (i >= total) return;
    int kn = K * N;
    int z = i / kn, rem = i - z * kn;
    int k = rem / N, n = rem - k * N;
    Wt[(size_t)z * kn + (size_t)n * K + k] = f2bf(W[i]);
}

// ================= CSR build =================
__global__ void csr_count(const int* __restrict__ eo, const int* __restrict__ ea,
                          const int* __restrict__ es, int* __restrict__ deg) {
    int e = blockIdx.x * 256 + threadIdx.x;
    if (e >= ETOT) return;
    int et = e >> 16, le = e & 65535;
    const int* ei = et == 0 ? eo : (et == 1 ? ea : es);
    atomicAdd(&deg[ei[EE + le]], 1);
}
__global__ void csr_alloc(const int* __restrict__ deg, int* __restrict__ counter,
                          int* __restrict__ rps) {
    int n = blockIdx.x * 256 + threadIdx.x;
    if (n < NN) rps[n] = atomicAdd(counter, deg[n]);
}
__global__ void csr_fill(const int* __restrict__ eo, const int* __restrict__ ea,
                         const int* __restrict__ es, const int* __restrict__ rps,
                         int* __restrict__ fill, int* __restrict__ elist) {
    int e = blockIdx.x * 256 + threadIdx.x;
    if (e >= ETOT) return;
    int et = e >> 16, le = e & 65535;
    const int* ei = et == 0 ? eo : (et == 1 ? ea : es);
    int src = ei[le], dst = ei[EE + le];
    int pos = rps[dst] + atomicAdd(&fill[dst], 1);
    elist[pos] = (et << 16) | src;
}

// ================= misc =================
__global__ void count_nodes(const int* __restrict__ batch, float* __restrict__ gcnt) {
    int n = blockIdx.x * 256 + threadIdx.x;
    if (n < NN) atomicAdd(&gcnt[batch[n]], 1.f);
}

__global__ __launch_bounds__(256) void enc_reduce(const float* __restrict__ h0, int c0, float* __restrict__ est) {
    float s1 = 0.f, s2 = 0.f;
    for (long i = blockIdx.x * 256 + threadIdx.x; i < (long)NN * 128; i += (long)gridDim.x * 256) {
        int n = (int)(i >> 7), j = (int)(i & 127);
        float v = h0[(size_t)n * FF + c0 + j];
        s1 += v; s2 += v * v;
    }
    s1 = wave_sum(s1);
    s2 = wave_sum(s2);
    if ((threadIdx.x & 63) == 0) { atomicAdd(&est[0], s1); atomicAdd(&est[1], s2); }
}

__global__ void enc_finalize(float* est) {
    int i = threadIdx.x;
    if (i < 3) {
        float cnt = (float)NN * 128.f;
        float mean = est[2 * i] / cnt;
        float var = est[2 * i + 1] / cnt - mean * mean;
        var = fmaxf(var, 0.f);
        est[6 + 2 * i] = mean;
        est[7 + 2 * i] = 1.f / (sqrtf(var) + 1e-5f);
    }
}

__global__ __launch_bounds__(256) void enc_apply(
    float* __restrict__ h0, unsigned short* __restrict__ hb, const float* __restrict__ est,
    const float* __restrict__ lw0, const float* __restrict__ lb0,
    const float* __restrict__ lw1, const float* __restrict__ lb1,
    const float* __restrict__ lw2, const float* __restrict__ lb2)
{
    long gt = (long)blockIdx.x * 256 + threadIdx.x;
    if (gt >= (long)NN * FF) return;
    int f = (int)(gt % FF);
    int enc = f >> 7, j = f & 127;
    const float* lw = enc == 0 ? lw0 : (enc == 1 ? lw1 : lw2);
    const float* lb = enc == 0 ? lb0 : (enc == 1 ? lb1 : lb2);
    float mean = est[6 + 2 * enc], sc = est[7 + 2 * enc];
    float v = (h0[gt] - mean) * sc * lw[j] + lb[j];
    h0[gt] = v;
    hb[gt] = f2bf(v);
}

// ================= qi/kj from bf16 xt =================
__global__ __launch_bounds__(128) void qk_kernel(
    const unsigned short* __restrict__ xt, const float* __restrict__ q, const float* __restrict__ k,
    float* __restrict__ qi, float* __restrict__ kj)
{
    __shared__ float qsT[8 * FF];
    __shared__ float ksT[8 * FF];
    for (int i = threadIdx.x; i < 8 * FF; i += 128) {
        int h = i & 7, f = i >> 3;
        qsT[h * FF + f] = q[i];
        ksT[h * FF + f] = k[i];
    }
    __syncthreads();
    int wid = (blockIdx.x * 128 + threadIdx.x) >> 6;  // r*NN + n
    int lane = threadIdx.x & 63;
    int f0 = lane * 6;
    const unsigned* row = (const unsigned*)(xt + (size_t)wid * FF) + lane * 3;
    unsigned u0 = row[0], u1 = row[1], u2 = row[2];
    float v[6] = {bflo(u0), bfhi(u0), bflo(u1), bfhi(u1), bflo(u2), bfhi(u2)};
    float aq[8] = {}, ak[8] = {};
#pragma unroll
    for (int i = 0; i < 6; ++i) {
        int f = f0 + i;
#pragma unroll
        for (int h = 0; h < 8; ++h) {
            aq[h] = fmaf(v[i], qsT[h * FF + f], aq[h]);
            ak[h] = fmaf(v[i], ksT[h * FF + f], ak[h]);
        }
    }
#pragma unroll
    for (int h = 0; h < 8; ++h) {
        float sq = wave_sum(aq[h]);
        float sk = wave_sum(ak[h]);
        if (lane == 0) {
            qi[(size_t)wid * 8 + h] = sq;
            kj[(size_t)wid * 8 + h] = sk;
        }
    }
}

// ================= fused per-dst edge pipeline + post (elu+residual+graph stats) =================
__global__ __launch_bounds__(256) void edge_fused(
    const int* __restrict__ rps, const int* __restrict__ deg, const int* __restrict__ elist,
    const float* __restrict__ qi, const float* __restrict__ kj,
    const unsigned short* __restrict__ xt,
    const float* __restrict__ hin, const float* __restrict__ rb, const int* __restrict__ batch,
    float* __restrict__ gs1, float* __restrict__ gs2, float* __restrict__ ybuf)
{
    int node = blockIdx.x * 4 + (threadIdx.x >> 6);
    int lane = threadIdx.x & 63;
    int d = deg[node], rp = rps[node];
    float m[8], s[8];
#pragma unroll
    for (int h = 0; h < 8; ++h) { m[h] = -3.4e38f; s[h] = 0.f; }
    // pass A: per-head max
    for (int base = 0; base < d; base += 64) {
        int e = base + lane;
        bool ok = e < d;
        int packed = ok ? elist[rp + e] : 0;
        int et = packed >> 16, src = packed & 0xFFFF;
        const float* qr = qi + ((size_t)et * NN + node) * 8;
        const float* kr = kj + ((size_t)et * NN + src) * 8;
#pragma unroll
        for (int h = 0; h < 8; ++h) {
            float av = qr[h] + kr[h];
            av = av >= 0.f ? av : NEG_SLOPE * av;
            av = ok ? av : -3.4e38f;
            m[h] = fmaxf(m[h], wave_max(av));
        }
    }
    // pass B: per-head sum of exp
    for (int base = 0; base < d; base += 64) {
        int e = base + lane;
        bool ok = e < d;
        int packed = ok ? elist[rp + e] : 0;
        int et = packed >> 16, src = packed & 0xFFFF;
        const float* qr = qi + ((size_t)et * NN + node) * 8;
        const float* kr = kj + ((size_t)et * NN + src) * 8;
#pragma unroll
        for (int h = 0; h < 8; ++h) {
            float av = qr[h] + kr[h];
            av = av >= 0.f ? av : NEG_SLOPE * av;
            float p = ok ? __expf(av - m[h]) : 0.f;
            s[h] += wave_sum(p);
        }
    }
    // pass C: feature-parallel weighted gather
    int f0 = lane * 6;
    int head = lane >> 3;
    float mh = m[head];
    float sh = s[head] + 1e-16f;
    float acc[6] = {};
    for (int e = 0; e < d; ++e) {
        int packed = elist[rp + e];
        int et = packed >> 16, src = packed & 0xFFFF;
        float av = qi[((size_t)et * NN + node) * 8 + head] + kj[((size_t)et * NN + src) * 8 + head];
        av = av >= 0.f ? av : NEG_SLOPE * av;
        float w = __expf(av - mh) / sh;
        const unsigned* xr = (const unsigned*)(xt + ((size_t)et * NN + src) * FF) + lane * 3;
        unsigned u0 = xr[0], u1 = xr[1], u2 = xr[2];
        acc[0] = fmaf(w, bflo(u0), acc[0]);
        acc[1] = fmaf(w, bfhi(u0), acc[1]);
        acc[2] = fmaf(w, bflo(u1), acc[2]);
        acc[3] = fmaf(w, bfhi(u1), acc[3]);
        acc[4] = fmaf(w, bflo(u2), acc[4]);
        acc[5] = fmaf(w, bfhi(u2), acc[5]);
    }
    // fused post: y = hin + elu(msg + rb), graph stats
    float s1 = 0.f, s2 = 0.f;
#pragma unroll
    for (int i = 0; i < 6; ++i) {
        int f = f0 + i;
        float mv = acc[i] + rb[f];
        float e = mv > 0.f ? mv : (__expf(mv) - 1.f);
        float y = hin[(size_t)node * FF + f] + e;
        ybuf[(size_t)node * FF + f] = y;
        s1 += y; s2 += y * y;
    }
    s1 = wave_sum(s1);
    s2 = wave_sum(s2);
    if (lane == 0) {
        int g = batch[node];
        atomicAdd(&gs1[g], s1);
        atomicAdd(&gs2[g], s2);
    }
}

__global__ void graph_finalize(
    const float* __restrict__ gcnt, const float* __restrict__ gs1, const float* __restrict__ gs2,
    float* __restrict__ gmean, float* __restrict__ grstd)
{
    int g = blockIdx.x * 64 + threadIdx.x;
    if (g >= GG) return;
    float cnt = fmaxf(gcnt[g], 1.f) * (float)FF;
    float mean = gs1[g] / cnt;
    float var = gs2[g] / cnt - mean * mean;
    var = fmaxf(var, 0.f);
    gmean[g] = mean;
    grstd[g] = 1.f / sqrtf(var + 1e-5f);
}

__global__ __launch_bounds__(256) void ln_apply(
    const float* __restrict__ y, const int* __restrict__ batch,
    const float* __restrict__ gmean, const float* __restrict__ grstd,
    const float* __restrict__ w, const float* __restrict__ b,
    float* __restrict__ hout, unsigned short* __restrict__ hb)
{
    long gt = (long)blockIdx.x * 256 + threadIdx.x;
    int n = (int)(gt >> 6);
    if (n >= NN) return;
    int lane = (int)(gt & 63);
    int f0 = lane * 6;
    int g = batch[n];
    float mean = gmean[g], rs = grstd[g];
#pragma unroll
    for (int i = 0; i < 6; ++i) {
        int f = f0 + i;
        float v = (y[(size_t)n * FF + f] - mean) * rs * w[f] + b[f];
        hout[(size_t)n * FF + f] = v;
        hb[(size_t)n * FF + f] = f2bf(v);
    }
}

// ================= host-side layer driver =================
static void rgat_layer(hipStream_t stream,
    const float* hin, const unsigned short* hbA,
    const float* rw, const float* rq, const float* rk, const float* rb,
    const float* lnw, const float* lnb,
    const int* rps, const int* deg, const int* elist, const int* batch,
    unsigned short* wt, unsigned short* xt, float* qi, float* kj,
    float* gs1, float* gs2, const float* gcnt, float* gmean, float* grstd,
    float* ybuf, float* hout, unsigned short* hbOut)
{
    hipMemsetAsync(gs1, 0, GG * 4, stream);
    hipMemsetAsync(gs2, 0, GG * 4, stream);
    int tt = 3 * FF * FF;
    transpose_bf<<<(tt + 255) / 256, 256, 0, stream>>>(rw, wt, FF, FF, tt);
    gemm_mfma<0, true, true><<<dim3(3, 384, 3), 256, 0, stream>>>(
        hbA, FF, wt, nullptr, xt, FF, (size_t)FF * FF, (size_t)NN * FF);
    qk_kernel<<<3 * NN / 2, 128, 0, stream>>>(xt, rq, rk, qi, kj);
    edge_fused<<<NN / 4, 256, 0, stream>>>(rps, deg, elist, qi, kj, xt, hin, rb, batch, gs1, gs2, ybuf);
    graph_finalize<<<GG / 64, 64, 0, stream>>>(gcnt, gs1, gs2, gmean, grstd);
    ln_apply<<<NN / 4, 256, 0, stream>>>(ybuf, batch, gmean, grstd, lnw, lnb, hout, hbOut);
}

extern "C" void kernel_launch(void* const* d_in, const int* in_sizes, int n_in,
                              void* d_out, int out_size, void* d_ws, size_t ws_size,
                              hipStream_t stream)
{
    const float* x_visual = (const float*)d_in[0];
    const float* x_geom   = (const float*)d_in[1];
    const float* x_prior  = (const float*)d_in[2];
    const float* vis_w  = (const float*)d_in[3];
    const float* vis_b  = (const float*)d_in[4];
    const float* vis_lw = (const float*)d_in[5];
    const float* vis_lb = (const float*)d_in[6];
    const float* geom_w  = (const float*)d_in[7];
    const float* geom_b  = (const float*)d_in[8];
    const float* geom_lw = (const float*)d_in[9];
    const float* geom_lb = (const float*)d_in[10];
    const float* prior_w  = (const float*)d_in[11];
    const float* prior_b  = (const float*)d_in[12];
    const float* prior_lw = (const float*)d_in[13];
    const float* prior_lb = (const float*)d_in[14];
    const float* r1_w = (const float*)d_in[15];
    const float* r1_q = (const float*)d_in[16];
    const float* r1_k = (const float*)d_in[17];
    const float* r1_b = (const float*)d_in[18];
    const float* n1_w = (const float*)d_in[19];
    const float* n1_b = (const float*)d_in[20];
    const float* r2_w = (const float*)d_in[21];
    const float* r2_q = (const float*)d_in[22];
    const float* r2_k = (const float*)d_in[23];
    const float* r2_b = (const float*)d_in[24];
    const float* n2_w = (const float*)d_in[25];
    const float* n2_b = (const float*)d_in[26];
    const float* c_w1 = (const float*)d_in[27];
    const float* c_b1 = (const float*)d_in[28];
    const float* c_w2 = (const float*)d_in[29];
    const float* c_b2 = (const float*)d_in[30];
    const int* ei_o  = (const int*)d_in[31];
    const int* ei_a  = (const int*)d_in[32];
    const int* ei_s  = (const int*)d_in[33];
    const int* batch = (const int*)d_in[34];
    float* out = (float*)d_out;

    char* p = (char*)d_ws;
    auto alloc = [&](size_t bytes) { char* r = p; p += (bytes + 255) & ~(size_t)255; return r; };
    float* h0 = (float*)alloc((size_t)NN * FF * 4);
    float* h1 = (float*)alloc((size_t)NN * FF * 4);
    float* ybuf = (float*)alloc((size_t)NN * FF * 4);
    unsigned short* xt = (unsigned short*)alloc((size_t)3 * NN * FF * 2);
    unsigned short* hb = (unsigned short*)alloc((size_t)NN * FF * 2);
    unsigned short* wt = (unsigned short*)alloc((size_t)3 * FF * FF * 2);
    float* t128 = (float*)alloc((size_t)NN * 128 * 4);
    float* qi = (float*)alloc((size_t)3 * NN * 8 * 4);
    float* kj = (float*)alloc((size_t)3 * NN * 8 * 4);
    int* deg = (int*)alloc(NN * 4);
    int* rps = (int*)alloc(NN * 4);
    int* fill = (int*)alloc(NN * 4);
    int* elist = (int*)alloc(ETOT * 4);
    int* counter = (int*)alloc(256);
    float* gs1 = (float*)alloc(GG * 4);
    float* gs2 = (float*)alloc(GG * 4);
    float* gcnt = (float*)alloc(GG * 4);
    float* gmean = (float*)alloc(GG * 4);
    float* grstd = (float*)alloc(GG * 4);
    float* est = (float*)alloc(64);
    float* h2 = h0;  // reuse

    // ---- CSR build (once; shared by both layers) ----
    hipMemsetAsync(deg, 0, NN * 4, stream);
    hipMemsetAsync(fill, 0, NN * 4, stream);
    hipMemsetAsync(counter, 0, 4, stream);
    csr_count<<<ETOT / 256, 256, 0, stream>>>(ei_o, ei_a, ei_s, deg);
    csr_alloc<<<NN / 256, 256, 0, stream>>>(deg, counter, rps);
    csr_fill<<<ETOT / 256, 256, 0, stream>>>(ei_o, ei_a, ei_s, rps, fill, elist);

    // ---- per-graph node counts ----
    hipMemsetAsync(gcnt, 0, GG * 4, stream);
    count_nodes<<<NN / 256, 256, 0, stream>>>(batch, gcnt);

    // ---- encoders ----
    hipMemsetAsync(est, 0, 64, stream);
    transpose_bf<<<(1024 * 128 + 255) / 256, 256, 0, stream>>>(vis_w, wt, 1024, 128, 1024 * 128);
    gemm_mfma<1, false, false><<<dim3(1, 384, 1), 256, 0, stream>>>(
        x_visual, 1024, wt, vis_b, h0, FF, 0, 0);
    gemm_k<1><<<dim3(2, 768, 1), 256, 0, stream>>>(x_geom, 6, geom_w, 128, geom_b, h0 + 128, FF, 128, 0, 0);
    gemm_k<1><<<dim3(2, 768, 1), 256, 0, stream>>>(x_prior, 50, prior_w, 128, prior_b, h0 + 256, FF, 128, 0, 0);
    enc_reduce<<<512, 256, 0, stream>>>(h0, 0, est + 0);
    enc_reduce<<<512, 256, 0, stream>>>(h0, 128, est + 2);
    enc_reduce<<<512, 256, 0, stream>>>(h0, 256, est + 4);
    enc_finalize<<<1, 64, 0, stream>>>(est);
    enc_apply<<<(int)((size_t)NN * FF / 256), 256, 0, stream>>>(
        h0, hb, est, vis_lw, vis_lb, geom_lw, geom_lb, prior_lw, prior_lb);

    // ---- RGAT layers ----
    rgat_layer(stream, h0, hb, r1_w, r1_q, r1_k, r1_b, n1_w, n1_b,
               rps, deg, elist, batch, wt, xt, qi, kj, gs1, gs2, gcnt, gmean, grstd,
               ybuf, h1, hb);
    rgat_layer(stream, h1, hb, r2_w, r2_q, r2_k, r2_b, n2_w, n2_b,
               rps, deg, elist, batch, wt, xt, qi, kj, gs1, gs2, gcnt, gmean, grstd,
               ybuf, h2, hb);

    // ---- classifier ----
    transpose_bf<<<(FF * 128 + 255) / 256, 256, 0, stream>>>(c_w1, wt, FF, 128, FF * 128);
    gemm_mfma<1, true, false><<<dim3(1, 384, 1), 256, 0, stream>>>(
        hb, FF, wt, c_b1, t128, 128, 0, 0);
    gemm_k<0><<<dim3(1, 768, 1), 256, 0, stream>>>(t128, 128, c_w2, 49, c_b2, out, 49, 49, 0, 0);
}

// Round 3
// 1088.582 us; speedup vs baseline: 6.7043x; 1.6610x over previous
//
#include <hip/hip_runtime.h>
#include <hip/hip_bf16.h>

#define NN 49152
#define GG 1024
#define EE 65536
#define ETOT 196608
#define FF 384
#define NEG_SLOPE 0.2f

typedef __attribute__((ext_vector_type(8))) short bf16x8;
typedef __attribute__((ext_vector_type(4))) float f32x4;

__device__ __forceinline__ float wave_sum(float v) {
#pragma unroll
    for (int m = 32; m; m >>= 1) v += __shfl_xor(v, m);
    return v;
}
__device__ __forceinline__ unsigned short f2bf(float f) {
    __hip_bfloat16 b = __float2bfloat16(f);
    return *reinterpret_cast<unsigned short*>(&b);
}
__device__ __forceinline__ float bflo(unsigned u) { return __uint_as_float(u << 16); }
__device__ __forceinline__ float bfhi(unsigned u) { return __uint_as_float(u & 0xffff0000u); }

// ================= MFMA bf16 GEMM: C = act(A @ Bt^T + bias) =================
__device__ __forceinline__ int swz(int row, int c16) {
    return row * 64 + ((c16 ^ ((row >> 1) & 3)) << 4);
}

template <int ACT, bool ABF, bool OBF>
__global__ __launch_bounds__(256) void gemm_mfma(
    const void* __restrict__ Ag, int K,
    const unsigned short* __restrict__ Btg,
    const float* __restrict__ bias,
    void* __restrict__ Cg, int ldc,
    size_t bzs, size_t czs)
{
    __shared__ __align__(16) char As[8192];
    __shared__ __align__(16) char Bs[8192];
    const unsigned short* Bt = Btg + (size_t)blockIdx.z * bzs;
    int t = threadIdx.x;
    int bm = blockIdx.y << 7, bn = blockIdx.x << 7;
    int lane = t & 63, wid = t >> 6, wr = wid >> 1, wc = wid & 1;
    f32x4 acc[4][4] = {};
    int ktn = K >> 5;
    for (int kt = 0; kt < ktn; ++kt) {
        int k0 = kt << 5;
#pragma unroll
        for (int ii = 0; ii < 2; ++ii) {
            int id = t + (ii << 8);
            int row = id >> 2, c16 = id & 3;
            char* dstA = As + swz(row, c16);
            if (ABF) {
                const unsigned short* srcA = (const unsigned short*)Ag + (size_t)(bm + row) * K + k0 + c16 * 8;
                *(int4*)dstA = *(const int4*)srcA;
            } else {
                const float* srcA = (const float*)Ag + (size_t)(bm + row) * K + k0 + c16 * 8;
                float4 a0 = *(const float4*)srcA;
                float4 a1 = *(const float4*)(srcA + 4);
                union { unsigned short u[8]; int4 v; } P;
                P.u[0] = f2bf(a0.x); P.u[1] = f2bf(a0.y); P.u[2] = f2bf(a0.z); P.u[3] = f2bf(a0.w);
                P.u[4] = f2bf(a1.x); P.u[5] = f2bf(a1.y); P.u[6] = f2bf(a1.z); P.u[7] = f2bf(a1.w);
                *(int4*)dstA = P.v;
            }
            const unsigned short* srcB = Bt + (size_t)(bn + row) * K + k0 + c16 * 8;
            *(int4*)(Bs + swz(row, c16)) = *(const int4*)srcB;
        }
        __syncthreads();
        int c16 = lane >> 4;
        bf16x8 af[4], bfr[4];
#pragma unroll
        for (int m = 0; m < 4; ++m)
            af[m] = *(const bf16x8*)(As + swz((wr << 6) + (m << 4) + (lane & 15), c16));
#pragma unroll
        for (int n = 0; n < 4; ++n)
            bfr[n] = *(const bf16x8*)(Bs + swz((wc << 6) + (n << 4) + (lane & 15), c16));
#pragma unroll
        for (int m = 0; m < 4; ++m)
#pragma unroll
            for (int n = 0; n < 4; ++n)
                acc[m][n] = __builtin_amdgcn_mfma_f32_16x16x32_bf16(af[m], bfr[n], acc[m][n], 0, 0, 0);
        __syncthreads();
    }
#pragma unroll
    for (int m = 0; m < 4; ++m) {
#pragma unroll
        for (int n = 0; n < 4; ++n) {
            int row0 = bm + (wr << 6) + (m << 4) + ((lane >> 4) << 2);
            int col = bn + (wc << 6) + (n << 4) + (lane & 15);
            float bv = bias ? bias[col] : 0.f;
#pragma unroll
            for (int j = 0; j < 4; ++j) {
                float v = acc[m][n][j] + bv;
                if (ACT == 1) v = fmaxf(v, 0.f);
                if (OBF) {
                    unsigned short* C = (unsigned short*)Cg + (size_t)blockIdx.z * czs;
                    C[(size_t)(row0 + j) * ldc + col] = f2bf(v);
                } else {
                    float* C = (float*)Cg + (size_t)blockIdx.z * czs;
                    C[(size_t)(row0 + j) * ldc + col] = v;
                }
            }
        }
    }
}

// ================= f32 fallback GEMM (small K / small N) =================
template <int ACT>
__global__ __launch_bounds__(256) void gemm_k(
    const float* __restrict__ A, int K,
    const float* __restrict__ Wg, int Jw,
    const float* __restrict__ bias,
    float* __restrict__ Cg, int ldc, int jmax,
    size_t wzs, size_t czs)
{
    __shared__ float Ash[16][64];
    __shared__ float Bsh[16][68];
    const float* W = Wg + (size_t)blockIdx.z * wzs;
    float* C = Cg + (size_t)blockIdx.z * czs;
    int tid = threadIdx.x;
    int bj = blockIdx.x << 6;
    int bm = blockIdx.y << 6;
    int tx = tid & 15, ty = tid >> 4;
    float acc[4][4] = {};
    int ktn = (K + 15) >> 4;
    int ar = tid >> 2;
    int aks = (tid & 3) << 2;
    int wk = tid >> 4;
    int wjs = (tid & 15) << 2;
    for (int kt = 0; kt < ktn; ++kt) {
        int k0 = kt << 4;
        const float* Ap = A + (size_t)(bm + ar) * K + k0 + aks;
#pragma unroll
        for (int i = 0; i < 4; ++i) {
            int k = k0 + aks + i;
            Ash[aks + i][ar] = (k < K) ? Ap[i] : 0.f;
        }
        const float* Wp = W + (size_t)(k0 + wk) * Jw + bj + wjs;
        bool kok = (k0 + wk) < K;
#pragma unroll
        for (int i = 0; i < 4; ++i) {
            int j = bj + wjs + i;
            Bsh[wk][wjs + i] = (kok && j < jmax) ? Wp[i] : 0.f;
        }
        __syncthreads();
#pragma unroll
        for (int kk = 0; kk < 16; ++kk) {
            const float4 av = *reinterpret_cast<const float4*>(&Ash[kk][ty << 2]);
            const float4 bv = *reinterpret_cast<const float4*>(&Bsh[kk][tx << 2]);
            float aa[4] = {av.x, av.y, av.z, av.w};
            float bb[4] = {bv.x, bv.y, bv.z, bv.w};
#pragma unroll
            for (int i = 0; i < 4; ++i)
#pragma unroll
                for (int j = 0; j < 4; ++j)
                    acc[i][j] = fmaf(aa[i], bb[j], acc[i][j]);
        }
        __syncthreads();
    }
#pragma unroll
    for (int i = 0; i < 4; ++i) {
        int row = bm + (ty << 2) + i;
#pragma unroll
        for (int j = 0; j < 4; ++j) {
            int col = bj + (tx << 2) + j;
            if (col < jmax) {
                float v = acc[i][j];
                if (bias) v += bias[col];
                if (ACT == 1) v = fmaxf(v, 0.f);
                C[(size_t)row * ldc + col] = v;
            }
        }
    }
}

// ================= weight transpose + bf16 convert =================
__global__ void transpose_bf(const float* __restrict__ W, unsigned short* __restrict__ Wt,
                             int K, int N, int total) {
    int i = blockIdx.x * 256 + threadIdx.x;
    if (i >= total) return;
    int kn = K * N;
    int z = i / kn, rem = i - z * kn;
    int k = rem / N, n = rem - k * N;
    Wt[(size_t)z * kn + (size_t)n * K + k] = f2bf(W[i]);
}

// ================= CSR build =================
__global__ void csr_count(const int* __restrict__ eo, const int* __restrict__ ea,
                          const int* __restrict__ es, int* __restrict__ deg) {
    int e = blockIdx.x * 256 + threadIdx.x;
    if (e >= ETOT) return;
    int et = e >> 16, le = e & 65535;
    const int* ei = et == 0 ? eo : (et == 1 ? ea : es);
    atomicAdd(&deg[ei[EE + le]], 1);
}
__global__ void csr_alloc(const int* __restrict__ deg, int* __restrict__ counter,
                          int* __restrict__ rps) {
    int n = blockIdx.x * 256 + threadIdx.x;
    if (n < NN) rps[n] = atomicAdd(counter, deg[n]);
}
__global__ void csr_fill(const int* __restrict__ eo, const int* __restrict__ ea,
                         const int* __restrict__ es, const int* __restrict__ rps,
                         int* __restrict__ fill, int* __restrict__ elist) {
    int e = blockIdx.x * 256 + threadIdx.x;
    if (e >= ETOT) return;
    int et = e >> 16, le = e & 65535;
    const int* ei = et == 0 ? eo : (et == 1 ? ea : es);
    int src = ei[le], dst = ei[EE + le];
    int pos = rps[dst] + atomicAdd(&fill[dst], 1);
    elist[pos] = (et << 16) | src;
}

// ================= misc =================
__global__ void count_nodes(const int* __restrict__ batch, float* __restrict__ gcnt) {
    int n = blockIdx.x * 256 + threadIdx.x;
    if (n < NN) atomicAdd(&gcnt[batch[n]], 1.f);
}

__global__ __launch_bounds__(256) void enc_reduce(const float* __restrict__ h0, int c0, float* __restrict__ est) {
    float s1 = 0.f, s2 = 0.f;
    for (long i = blockIdx.x * 256 + threadIdx.x; i < (long)NN * 128; i += (long)gridDim.x * 256) {
        int n = (int)(i >> 7), j = (int)(i & 127);
        float v = h0[(size_t)n * FF + c0 + j];
        s1 += v; s2 += v * v;
    }
    s1 = wave_sum(s1);
    s2 = wave_sum(s2);
    if ((threadIdx.x & 63) == 0) { atomicAdd(&est[0], s1); atomicAdd(&est[1], s2); }
}

__global__ void enc_finalize(float* est) {
    int i = threadIdx.x;
    if (i < 3) {
        float cnt = (float)NN * 128.f;
        float mean = est[2 * i] / cnt;
        float var = est[2 * i + 1] / cnt - mean * mean;
        var = fmaxf(var, 0.f);
        est[6 + 2 * i] = mean;
        est[7 + 2 * i] = 1.f / (sqrtf(var) + 1e-5f);
    }
}

__global__ __launch_bounds__(256) void enc_apply(
    float* __restrict__ h0, unsigned short* __restrict__ hb, const float* __restrict__ est,
    const float* __restrict__ lw0, const float* __restrict__ lb0,
    const float* __restrict__ lw1, const float* __restrict__ lb1,
    const float* __restrict__ lw2, const float* __restrict__ lb2)
{
    long gt = (long)blockIdx.x * 256 + threadIdx.x;
    if (gt >= (long)NN * FF) return;
    int f = (int)(gt % FF);
    int enc = f >> 7, j = f & 127;
    const float* lw = enc == 0 ? lw0 : (enc == 1 ? lw1 : lw2);
    const float* lb = enc == 0 ? lb0 : (enc == 1 ? lb1 : lb2);
    float mean = est[6 + 2 * enc], sc = est[7 + 2 * enc];
    float v = (h0[gt] - mean) * sc * lw[j] + lb[j];
    h0[gt] = v;
    hb[gt] = f2bf(v);
}

// ================= qi/kj via MFMA: [3N,384] @ [384,16] =================
// one wave per 16 rows; B = concat(q^T, k^T) in LDS (padded stride 392 -> 2-way=free)
__global__ __launch_bounds__(256) void qk_mfma(
    const unsigned short* __restrict__ xt,
    const float* __restrict__ q, const float* __restrict__ k,
    float* __restrict__ qi, float* __restrict__ kj)
{
    __shared__ __align__(16) unsigned short qkT[16 * 392];
    int t = threadIdx.x;
    for (int idx = t; idx < 16 * 384; idx += 256) {
        int row = idx / 384, f = idx - row * 384;
        float v = (row < 8) ? q[f * 8 + row] : k[f * 8 + row - 8];
        qkT[row * 392 + f] = f2bf(v);
    }
    __syncthreads();
    int lane = t & 63, wid = t >> 6;
    int col = lane & 15, kq = lane >> 4;
    bf16x8 bfrag[12];
#pragma unroll
    for (int kt = 0; kt < 12; ++kt)
        bfrag[kt] = *(const bf16x8*)(qkT + col * 392 + kt * 32 + kq * 8);
    int tile = blockIdx.x * 4 + wid;
    const unsigned short* arow = xt + (size_t)(tile * 16 + col) * FF + kq * 8;
    f32x4 acc = {};
#pragma unroll
    for (int kt = 0; kt < 12; ++kt) {
        bf16x8 af = *(const bf16x8*)(arow + kt * 32);
        acc = __builtin_amdgcn_mfma_f32_16x16x32_bf16(af, bfrag[kt], acc, 0, 0, 0);
    }
    int row0 = kq << 2;
#pragma unroll
    for (int j = 0; j < 4; ++j) {
        size_t node = (size_t)tile * 16 + row0 + j;  // row in [0, 3*NN)
        float v = acc[j];
        if (col < 8) qi[node * 8 + col] = v;
        else         kj[node * 8 + col - 8] = v;
    }
}

// ================= per-(node,head) softmax: w = exp(alpha-m), sden = 1/sum =================
__global__ __launch_bounds__(256) void msum_kernel(
    const int* __restrict__ rps, const int* __restrict__ deg, const int* __restrict__ elist,
    const float* __restrict__ qi, const float* __restrict__ kj,
    float* __restrict__ w, float* __restrict__ sden)
{
    int t = blockIdx.x * 256 + threadIdx.x;  // node*8 + h
    if (t >= NN * 8) return;
    int node = t >> 3, h = t & 7;
    int d = deg[node], rp = rps[node];
    float qv0 = qi[(size_t)node * 8 + h];
    float qv1 = qi[((size_t)NN + node) * 8 + h];
    float qv2 = qi[((size_t)2 * NN + node) * 8 + h];
    float m = -3.4e38f;
    for (int e = 0; e < d; ++e) {
        int packed = elist[rp + e];
        int et = packed >> 16, src = packed & 0xFFFF;
        float qv = et == 0 ? qv0 : (et == 1 ? qv1 : qv2);
        float av = qv + kj[((size_t)et * NN + src) * 8 + h];
        av = av >= 0.f ? av : NEG_SLOPE * av;
        m = fmaxf(m, av);
    }
    float s = 0.f;
    for (int e = 0; e < d; ++e) {
        int packed = elist[rp + e];
        int et = packed >> 16, src = packed & 0xFFFF;
        float qv = et == 0 ? qv0 : (et == 1 ? qv1 : qv2);
        float av = qv + kj[((size_t)et * NN + src) * 8 + h];
        av = av >= 0.f ? av : NEG_SLOPE * av;
        float p = __expf(av - m);
        w[(size_t)(rp + e) * 8 + h] = p;
        s += p;
    }
    sden[t] = 1.f / (s + 1e-16f);
}

// ================= weighted gather + elu + residual + graph stats =================
__global__ __launch_bounds__(256) void gather_fused(
    const int* __restrict__ rps, const int* __restrict__ deg, const int* __restrict__ elist,
    const float* __restrict__ w, const float* __restrict__ sden,
    const unsigned short* __restrict__ xt,
    const float* __restrict__ hin, const float* __restrict__ rb, const int* __restrict__ batch,
    float* __restrict__ gs1, float* __restrict__ gs2, float* __restrict__ ybuf)
{
    int node = blockIdx.x * 4 + (threadIdx.x >> 6);
    int lane = threadIdx.x & 63;
    int d = deg[node], rp = rps[node];
    int head = lane >> 3;
    float inv = sden[node * 8 + head];
    int f0 = lane * 6;
    float acc[6] = {};
    for (int e = 0; e < d; ++e) {
        int packed = elist[rp + e];
        int et = packed >> 16, src = packed & 0xFFFF;
        float wgt = w[(size_t)(rp + e) * 8 + head] * inv;
        const unsigned* xr = (const unsigned*)(xt + ((size_t)et * NN + src) * FF) + lane * 3;
        unsigned u0 = xr[0], u1 = xr[1], u2 = xr[2];
        acc[0] = fmaf(wgt, bflo(u0), acc[0]);
        acc[1] = fmaf(wgt, bfhi(u0), acc[1]);
        acc[2] = fmaf(wgt, bflo(u1), acc[2]);
        acc[3] = fmaf(wgt, bfhi(u1), acc[3]);
        acc[4] = fmaf(wgt, bflo(u2), acc[4]);
        acc[5] = fmaf(wgt, bfhi(u2), acc[5]);
    }
    float s1 = 0.f, s2 = 0.f;
#pragma unroll
    for (int i = 0; i < 6; ++i) {
        int f = f0 + i;
        float mv = acc[i] + rb[f];
        float e = mv > 0.f ? mv : (__expf(mv) - 1.f);
        float y = hin[(size_t)node * FF + f] + e;
        ybuf[(size_t)node * FF + f] = y;
        s1 += y; s2 += y * y;
    }
    s1 = wave_sum(s1);
    s2 = wave_sum(s2);
    if (lane == 0) {
        int g = batch[node];
        atomicAdd(&gs1[g], s1);
        atomicAdd(&gs2[g], s2);
    }
}

__global__ void graph_finalize(
    const float* __restrict__ gcnt, const float* __restrict__ gs1, const float* __restrict__ gs2,
    float* __restrict__ gmean, float* __restrict__ grstd)
{
    int g = blockIdx.x * 64 + threadIdx.x;
    if (g >= GG) return;
    float cnt = fmaxf(gcnt[g], 1.f) * (float)FF;
    float mean = gs1[g] / cnt;
    float var = gs2[g] / cnt - mean * mean;
    var = fmaxf(var, 0.f);
    gmean[g] = mean;
    grstd[g] = 1.f / sqrtf(var + 1e-5f);
}

__global__ __launch_bounds__(256) void ln_apply(
    const float* __restrict__ y, const int* __restrict__ batch,
    const float* __restrict__ gmean, const float* __restrict__ grstd,
    const float* __restrict__ w, const float* __restrict__ b,
    float* __restrict__ hout, unsigned short* __restrict__ hb)
{
    long gt = (long)blockIdx.x * 256 + threadIdx.x;
    int n = (int)(gt >> 6);
    if (n >= NN) return;
    int lane = (int)(gt & 63);
    int f0 = lane * 6;
    int g = batch[n];
    float mean = gmean[g], rs = grstd[g];
#pragma unroll
    for (int i = 0; i < 6; ++i) {
        int f = f0 + i;
        float v = (y[(size_t)n * FF + f] - mean) * rs * w[f] + b[f];
        hout[(size_t)n * FF + f] = v;
        hb[(size_t)n * FF + f] = f2bf(v);
    }
}

// ================= host-side layer driver =================
static void rgat_layer(hipStream_t stream,
    const float* hin, const unsigned short* hbA,
    const float* rw, const float* rq, const float* rk, const float* rb,
    const float* lnw, const float* lnb,
    const int* rps, const int* deg, const int* elist, const int* batch,
    unsigned short* wt, unsigned short* xt, float* qi, float* kj,
    float* wbuf, float* sden,
    float* gs1, float* gs2, const float* gcnt, float* gmean, float* grstd,
    float* ybuf, float* hout, unsigned short* hbOut)
{
    hipMemsetAsync(gs1, 0, GG * 4, stream);
    hipMemsetAsync(gs2, 0, GG * 4, stream);
    int tt = 3 * FF * FF;
    transpose_bf<<<(tt + 255) / 256, 256, 0, stream>>>(rw, wt, FF, FF, tt);
    gemm_mfma<0, true, true><<<dim3(3, 384, 3), 256, 0, stream>>>(
        hbA, FF, wt, nullptr, xt, FF, (size_t)FF * FF, (size_t)NN * FF);
    qk_mfma<<<3 * NN / 64, 256, 0, stream>>>(xt, rq, rk, qi, kj);
    msum_kernel<<<NN * 8 / 256, 256, 0, stream>>>(rps, deg, elist, qi, kj, wbuf, sden);
    gather_fused<<<NN / 4, 256, 0, stream>>>(rps, deg, elist, wbuf, sden, xt, hin, rb, batch, gs1, gs2, ybuf);
    graph_finalize<<<GG / 64, 64, 0, stream>>>(gcnt, gs1, gs2, gmean, grstd);
    ln_apply<<<NN / 4, 256, 0, stream>>>(ybuf, batch, gmean, grstd, lnw, lnb, hout, hbOut);
}

extern "C" void kernel_launch(void* const* d_in, const int* in_sizes, int n_in,
                              void* d_out, int out_size, void* d_ws, size_t ws_size,
                              hipStream_t stream)
{
    const float* x_visual = (const float*)d_in[0];
    const float* x_geom   = (const float*)d_in[1];
    const float* x_prior  = (const float*)d_in[2];
    const float* vis_w  = (const float*)d_in[3];
    const float* vis_b  = (const float*)d_in[4];
    const float* vis_lw = (const float*)d_in[5];
    const float* vis_lb = (const float*)d_in[6];
    const float* geom_w  = (const float*)d_in[7];
    const float* geom_b  = (const float*)d_in[8];
    const float* geom_lw = (const float*)d_in[9];
    const float* geom_lb = (const float*)d_in[10];
    const float* prior_w  = (const float*)d_in[11];
    const float* prior_b  = (const float*)d_in[12];
    const float* prior_lw = (const float*)d_in[13];
    const float* prior_lb = (const float*)d_in[14];
    const float* r1_w = (const float*)d_in[15];
    const float* r1_q = (const float*)d_in[16];
    const float* r1_k = (const float*)d_in[17];
    const float* r1_b = (const float*)d_in[18];
    const float* n1_w = (const float*)d_in[19];
    const float* n1_b = (const float*)d_in[20];
    const float* r2_w = (const float*)d_in[21];
    const float* r2_q = (const float*)d_in[22];
    const float* r2_k = (const float*)d_in[23];
    const float* r2_b = (const float*)d_in[24];
    const float* n2_w = (const float*)d_in[25];
    const float* n2_b = (const float*)d_in[26];
    const float* c_w1 = (const float*)d_in[27];
    const float* c_b1 = (const float*)d_in[28];
    const float* c_w2 = (const float*)d_in[29];
    const float* c_b2 = (const float*)d_in[30];
    const int* ei_o  = (const int*)d_in[31];
    const int* ei_a  = (const int*)d_in[32];
    const int* ei_s  = (const int*)d_in[33];
    const int* batch = (const int*)d_in[34];
    float* out = (float*)d_out;

    char* p = (char*)d_ws;
    auto alloc = [&](size_t bytes) { char* r = p; p += (bytes + 255) & ~(size_t)255; return r; };
    float* h0 = (float*)alloc((size_t)NN * FF * 4);
    float* h1 = (float*)alloc((size_t)NN * FF * 4);
    float* ybuf = (float*)alloc((size_t)NN * FF * 4);
    unsigned short* xt = (unsigned short*)alloc((size_t)3 * NN * FF * 2);
    unsigned short* hb = (unsigned short*)alloc((size_t)NN * FF * 2);
    unsigned short* wt = (unsigned short*)alloc((size_t)3 * FF * FF * 2);
    float* t128 = (float*)alloc((size_t)NN * 128 * 4);
    float* qi = (float*)alloc((size_t)3 * NN * 8 * 4);
    float* kj = (float*)alloc((size_t)3 * NN * 8 * 4);
    float* wbuf = (float*)alloc((size_t)ETOT * 8 * 4);
    float* sden = (float*)alloc((size_t)NN * 8 * 4);
    int* deg = (int*)alloc(NN * 4);
    int* rps = (int*)alloc(NN * 4);
    int* fill = (int*)alloc(NN * 4);
    int* elist = (int*)alloc(ETOT * 4);
    int* counter = (int*)alloc(256);
    float* gs1 = (float*)alloc(GG * 4);
    float* gs2 = (float*)alloc(GG * 4);
    float* gcnt = (float*)alloc(GG * 4);
    float* gmean = (float*)alloc(GG * 4);
    float* grstd = (float*)alloc(GG * 4);
    float* est = (float*)alloc(64);
    float* h2 = h0;  // reuse

    // ---- CSR build (once; shared by both layers) ----
    hipMemsetAsync(deg, 0, NN * 4, stream);
    hipMemsetAsync(fill, 0, NN * 4, stream);
    hipMemsetAsync(counter, 0, 4, stream);
    csr_count<<<ETOT / 256, 256, 0, stream>>>(ei_o, ei_a, ei_s, deg);
    csr_alloc<<<NN / 256, 256, 0, stream>>>(deg, counter, rps);
    csr_fill<<<ETOT / 256, 256, 0, stream>>>(ei_o, ei_a, ei_s, rps, fill, elist);

    // ---- per-graph node counts ----
    hipMemsetAsync(gcnt, 0, GG * 4, stream);
    count_nodes<<<NN / 256, 256, 0, stream>>>(batch, gcnt);

    // ---- encoders ----
    hipMemsetAsync(est, 0, 64, stream);
    transpose_bf<<<(1024 * 128 + 255) / 256, 256, 0, stream>>>(vis_w, wt, 1024, 128, 1024 * 128);
    gemm_mfma<1, false, false><<<dim3(1, 384, 1), 256, 0, stream>>>(
        x_visual, 1024, wt, vis_b, h0, FF, 0, 0);
    gemm_k<1><<<dim3(2, 768, 1), 256, 0, stream>>>(x_geom, 6, geom_w, 128, geom_b, h0 + 128, FF, 128, 0, 0);
    gemm_k<1><<<dim3(2, 768, 1), 256, 0, stream>>>(x_prior, 50, prior_w, 128, prior_b, h0 + 256, FF, 128, 0, 0);
    enc_reduce<<<512, 256, 0, stream>>>(h0, 0, est + 0);
    enc_reduce<<<512, 256, 0, stream>>>(h0, 128, est + 2);
    enc_reduce<<<512, 256, 0, stream>>>(h0, 256, est + 4);
    enc_finalize<<<1, 64, 0, stream>>>(est);
    enc_apply<<<(int)((size_t)NN * FF / 256), 256, 0, stream>>>(
        h0, hb, est, vis_lw, vis_lb, geom_lw, geom_lb, prior_lw, prior_lb);

    // ---- RGAT layers ----
    rgat_layer(stream, h0, hb, r1_w, r1_q, r1_k, r1_b, n1_w, n1_b,
               rps, deg, elist, batch, wt, xt, qi, kj, wbuf, sden,
               gs1, gs2, gcnt, gmean, grstd, ybuf, h1, hb);
    rgat_layer(stream, h1, hb, r2_w, r2_q, r2_k, r2_b, n2_w, n2_b,
               rps, deg, elist, batch, wt, xt, qi, kj, wbuf, sden,
               gs1, gs2, gcnt, gmean, grstd, ybuf, h2, hb);

    // ---- classifier ----
    transpose_bf<<<(FF * 128 + 255) / 256, 256, 0, stream>>>(c_w1, wt, FF, 128, FF * 128);
    gemm_mfma<1, true, false><<<dim3(1, 384, 1), 256, 0, stream>>>(
        hb, FF, wt, c_b1, t128, 128, 0, 0);
    gemm_k<0><<<dim3(1, 768, 1), 256, 0, stream>>>(t128, 128, c_w2, 49, c_b2, out, 49, 49, 0, 0);
}